// Round 4
// baseline (2030.110 us; speedup 1.0000x reference)
//
#include <hip/hip_runtime.h>

// EIRNN: B=256,T=512,I=128,H=512,O=64; alpha=0.2, softplus beta=8, thresh=20.
// R4: tag-in-data exchange (R3) with ALL global atomics removed.
// h element stored as u32 {tag=t+1 | f16(h)}, relaxed agent-scope (sc1)
// dword stores = single-copy atomic -> consumer gather loads ARE the poll
// (retry stale u64s). R3's regression was contended y atomicAdds outstanding
// during the spin: every retry round's s_waitcnt vmcnt(0) waited for 8-way
// same-address RMW acks at the coherence point. R4 readout: K-split across
// the block's 4 waves (each K=128, this block's 8 O-cols) -> LDS ds_add_f32
// into double-buffered ysum -> plain deferred stores. No atomics, no memset.
// ABA-safe: lock-step prevents slot reuse; tag exact for t<=512; ws poison
// 0xAAAA matches no tag.

#define BB 256
#define TT 512
#define II 128
#define HH 512
#define OO 64
#define RG 16   // batch rows per row-group
#define JC 64   // h-columns per shard block
#define NG 16   // row-groups
#define NC 8    // shard blocks per group
#define HGP (HH + 8)
#define XP  (II + 8)

typedef _Float16 f16;
typedef f16 f16x8 __attribute__((ext_vector_type(8)));
typedef float f32x4 __attribute__((ext_vector_type(4)));

__global__ __launch_bounds__(256, 1)
void eirnn_persist(const float* __restrict__ x,
                   const float* __restrict__ Wxh,
                   const float* __restrict__ Whh,
                   const float* __restrict__ bh,
                   const float* __restrict__ Wout,
                   const float* __restrict__ bout,
                   float* __restrict__ yout,
                   unsigned int* __restrict__ hbuf)  // [2][BB][HH] u32 (1 MB)
{
    const int tid  = threadIdx.x;
    const int bid  = blockIdx.x;
    const int wave = tid >> 6;
    const int lane = tid & 63;
    const int quad = lane >> 4;
    const int l16  = lane & 15;
    const int r    = bid >> 3;        // row-group
    const int c    = bid & 7;         // shard
    const int rowbase = r * RG;
    const int jbase   = c * JC;
    const int myrow   = wave * 16 + l16;

    __shared__ __align__(16) f16 hg[2][RG][HGP];   // double-buffered gathered h
    __shared__ __align__(16) f16 xsh[2][RG][XP];   // double-buffered x_t
    __shared__ float ysum[2][RG][8];               // readout wave-partial sums

    // ---- one-time: weight shards -> constant register B-fragments ----
    f16x8 bf[16];   // W_hh shard, K=512
    f16x8 xbf[4];   // W_xh shard, K=128
    f16x8 bfo[4];   // W_out rows [c*8,c*8+8), K-slice [wave*128, +128)
    {
        const float* wp = Whh + (size_t)(jbase + myrow) * HH + quad * 8;
        #pragma unroll
        for (int ks = 0; ks < 16; ++ks) {
            float4 u = *(const float4*)(wp + ks * 32);
            float4 v = *(const float4*)(wp + ks * 32 + 4);
            f16x8 tv;
            tv[0]=(f16)u.x; tv[1]=(f16)u.y; tv[2]=(f16)u.z; tv[3]=(f16)u.w;
            tv[4]=(f16)v.x; tv[5]=(f16)v.y; tv[6]=(f16)v.z; tv[7]=(f16)v.w;
            bf[ks] = tv;
        }
        const float* wq = Wxh + (size_t)(jbase + myrow) * II + quad * 8;
        #pragma unroll
        for (int ks = 0; ks < 4; ++ks) {
            float4 u = *(const float4*)(wq + ks * 32);
            float4 v = *(const float4*)(wq + ks * 32 + 4);
            f16x8 tv;
            tv[0]=(f16)u.x; tv[1]=(f16)u.y; tv[2]=(f16)u.z; tv[3]=(f16)u.w;
            tv[4]=(f16)v.x; tv[5]=(f16)v.y; tv[6]=(f16)v.z; tv[7]=(f16)v.w;
            xbf[ks] = tv;
        }
        #pragma unroll
        for (int ks = 0; ks < 4; ++ks) {
            f16x8 tv = (f16x8)(f16)0.f;
            if (l16 < 8) {
                const float* wo = Wout + (size_t)(c * 8 + l16) * HH
                                + wave * 128 + ks * 32 + quad * 8;
                float4 u = *(const float4*)(wo);
                float4 v = *(const float4*)(wo + 4);
                tv[0]=(f16)u.x; tv[1]=(f16)u.y; tv[2]=(f16)u.z; tv[3]=(f16)u.w;
                tv[4]=(f16)v.x; tv[5]=(f16)v.y; tv[6]=(f16)v.z; tv[7]=(f16)v.w;
            }
            bfo[ks] = tv;
        }
    }
    const float biash = bh[jbase + myrow];
    const float boutv = (tid < 128) ? bout[c * 8 + (tid & 7)] : 0.0f;

    // zero hg[0] (t=0 uses h_0=0) and ysum
    for (int p = tid; p < RG * HGP / 2; p += 256)
        ((unsigned int*)hg[0])[p] = 0u;
    ((float*)ysum)[tid] = 0.f;   // 2*16*8 = 256 floats

    // fp32 integrator state: lane owns h[m=quad*4+reg][jbase+myrow]
    float hreg[4] = {0.f, 0.f, 0.f, 0.f};

    // gather geometry: thread owns cols {2*tid, 2*tid+1} of ALL 16 rows.
    const bool own = ((tid >> 5) == c);

    // x prefetch for t=0
    float4 xpf0, xpf1;
    {
        int p0 = tid, p1 = tid + 256;
        xpf0 = ((const float4*)(x + ((size_t)(rowbase + (p0 >> 5)) * TT + 0) * II))[p0 & 31];
        xpf1 = ((const float4*)(x + ((size_t)(rowbase + (p1 >> 5)) * TT + 0) * II))[p1 & 31];
    }

    for (int t = 0; t <= TT; ++t) {
        const int p = t & 1;

        // ---- stage x_t, then issue x_{t+1} prefetch ----
        if (t < TT) {
            int p0 = tid, p1 = tid + 256;
            f16* d0 = &xsh[p][p0 >> 5][(p0 & 31) * 4];
            d0[0]=(f16)xpf0.x; d0[1]=(f16)xpf0.y; d0[2]=(f16)xpf0.z; d0[3]=(f16)xpf0.w;
            f16* d1 = &xsh[p][p1 >> 5][(p1 & 31) * 4];
            d1[0]=(f16)xpf1.x; d1[1]=(f16)xpf1.y; d1[2]=(f16)xpf1.z; d1[3]=(f16)xpf1.w;
            if (t + 1 < TT) {
                xpf0 = ((const float4*)(x + ((size_t)(rowbase + (p0 >> 5)) * TT + (t + 1)) * II))[p0 & 31];
                xpf1 = ((const float4*)(x + ((size_t)(rowbase + (p1 >> 5)) * TT + (t + 1)) * II))[p1 & 31];
            }
        }

        // ---- tagged gather of h(t): loads ARE the poll; retry stale u64s ----
        if (t >= 1 && !own) {
            const unsigned tg = (unsigned)t;
            const unsigned long long* src = (const unsigned long long*)hbuf
                + (size_t)p * (BB * HH / 2) + (size_t)rowbase * (HH / 2) + tid;
            unsigned long long v[16];
            #pragma unroll
            for (int k = 0; k < 16; ++k)
                v[k] = __hip_atomic_load(src + (size_t)k * (HH / 2),
                                         __ATOMIC_RELAXED, __HIP_MEMORY_SCOPE_AGENT);
            unsigned pend = 0xffffu;
            while (pend) {
                unsigned np = 0;
                #pragma unroll
                for (int k = 0; k < 16; ++k) {
                    if (pend & (1u << k)) {
                        unsigned lo = (unsigned)v[k];
                        unsigned hi = (unsigned)(v[k] >> 32);
                        if (((lo >> 16) == tg) & ((hi >> 16) == tg)) {
                            *(unsigned int*)&hg[p][k][2 * tid] = (lo & 0xffffu) | (hi << 16);
                        } else {
                            np |= (1u << k);
                        }
                    }
                }
                pend = np;
                if (np) {
                    #pragma unroll
                    for (int k = 0; k < 16; ++k)
                        if (np & (1u << k))
                            v[k] = __hip_atomic_load(src + (size_t)k * (HH / 2),
                                                     __ATOMIC_RELAXED, __HIP_MEMORY_SCOPE_AGENT);
                }
            }
        }
        __syncthreads();   // single barrier per step

        if (t < TT) {
            // pre = h_t.W_hh^T + x_t.W_xh^T + b_h
            f32x4 acc0 = {0.f,0.f,0.f,0.f}, acc1 = {0.f,0.f,0.f,0.f};
            #pragma unroll
            for (int ks = 0; ks < 16; ks += 2) {
                f16x8 a0 = *(const f16x8*)&hg[p][l16][ks * 32 + quad * 8];
                f16x8 a1 = *(const f16x8*)&hg[p][l16][(ks + 1) * 32 + quad * 8];
                acc0 = __builtin_amdgcn_mfma_f32_16x16x32_f16(a0, bf[ks], acc0, 0, 0, 0);
                acc1 = __builtin_amdgcn_mfma_f32_16x16x32_f16(a1, bf[ks + 1], acc1, 0, 0, 0);
            }
            #pragma unroll
            for (int ks = 0; ks < 4; ks += 2) {
                f16x8 a0 = *(const f16x8*)&xsh[p][l16][ks * 32 + quad * 8];
                f16x8 a1 = *(const f16x8*)&xsh[p][l16][(ks + 1) * 32 + quad * 8];
                acc0 = __builtin_amdgcn_mfma_f32_16x16x32_f16(a0, xbf[ks], acc0, 0, 0, 0);
                acc1 = __builtin_amdgcn_mfma_f32_16x16x32_f16(a1, xbf[ks + 1], acc1, 0, 0, 0);
            }
            // phi + leaky update; fire-and-forget tagged u32 stores (no drain)
            unsigned int* dst = hbuf + (size_t)((t + 1) & 1) * (BB * HH);
            const unsigned tg1 = (unsigned)(t + 1) << 16;
            #pragma unroll
            for (int reg = 0; reg < 4; ++reg) {
                float pre = acc0[reg] + acc1[reg] + biash;
                float z = 8.f * pre;
                float ph = (z > 20.f) ? pre : (__logf(1.f + __expf(z)) * 0.125f);
                float hn = 0.8f * hreg[reg] + 0.2f * ph;
                hreg[reg] = hn;
                f16 h16 = (f16)hn;
                hg[1 - p][quad * 4 + reg][jbase + myrow] = h16;   // self short-circuit
                unsigned hb = (unsigned)__builtin_bit_cast(unsigned short, h16);
                __hip_atomic_store(dst + (size_t)(rowbase + quad * 4 + reg) * HH + jbase + myrow,
                                   tg1 | hb, __ATOMIC_RELAXED, __HIP_MEMORY_SCOPE_AGENT);
            }
        }

        // ---- readout: accumulate y_{t-1} partials (K=128 per wave) into ysum[p] ----
        if (t >= 1) {
            f32x4 ya = {0.f,0.f,0.f,0.f};
            #pragma unroll
            for (int ks = 0; ks < 4; ++ks) {
                f16x8 a = *(const f16x8*)&hg[p][l16][wave * 128 + ks * 32 + quad * 8];
                ya = __builtin_amdgcn_mfma_f32_16x16x32_f16(a, bfo[ks], ya, 0, 0, 0);
            }
            if (l16 < 8) {
                #pragma unroll
                for (int reg = 0; reg < 4; ++reg)
                    atomicAdd(&ysum[p][quad * 4 + reg][l16], ya[reg]);  // ds_add_f32
            }
        }
        // ---- deferred y store: ysum[1-p] holds y_{t-2} (complete per barrier) ----
        if (t >= 2 && tid < 128) {
            int row = tid >> 3, col = tid & 7;
            float yv = ysum[1 - p][row][col] + boutv;
            ysum[1 - p][row][col] = 0.f;
            yout[((size_t)(rowbase + row) * TT + (t - 2)) * OO + c * 8 + col] = yv;
        }
    }

    // final: y_{511} partials sit in ysum[TT&1 = 0]
    __syncthreads();
    if (tid < 128) {
        int row = tid >> 3, col = tid & 7;
        yout[((size_t)(rowbase + row) * TT + (TT - 1)) * OO + c * 8 + col]
            = ysum[0][row][col] + boutv;
    }
}

extern "C" void kernel_launch(void* const* d_in, const int* in_sizes, int n_in,
                              void* d_out, int out_size, void* d_ws, size_t ws_size,
                              hipStream_t stream)
{
    const float* x    = (const float*)d_in[0];
    const float* Wxh  = (const float*)d_in[1];
    const float* Whh  = (const float*)d_in[2];
    const float* bh   = (const float*)d_in[3];
    const float* Wout = (const float*)d_in[4];
    const float* bout = (const float*)d_in[5];
    float* yout = (float*)d_out;

    unsigned int* hbuf = (unsigned int*)d_ws;           // [2][BB][HH] u32 = 1 MB
    const size_t hbuf_bytes = (size_t)2 * BB * HH * sizeof(unsigned int);
    if (ws_size < hbuf_bytes) return;

    // y fully written by plain stores (each element exactly once) -> no memset.
    // hbuf poison tag 0xAAAA matches no t in [1,512] -> no init needed.
    eirnn_persist<<<dim3(NG * NC), dim3(256), 0, stream>>>(
        x, Wxh, Whh, bh, Wout, bout, yout, hbuf);
}